// Round 1
// baseline (1602.780 us; speedup 1.0000x reference)
//
#include <hip/hip_runtime.h>
#include <stdint.h>

#define HW      262144u      // 512*512
#define NPIX    1048576u     // 4*HW  (pixel index fits in 20 bits)
#define MAXC    131072u      // candidate list capacity per side (~87k expected)
#define NSEL    2048u        // POS_NUM*B = NEG_NUM*B
#define TPTS    4096u        // total selected points

// state region word offsets (uint32 words)
#define S_HIST   0           // hist[4 rounds][2 lists][2048]
#define S_CNT    16384       // cnt[2]
#define S_KK     16386       // remaining-rank k[2]
#define S_PREFIX 16388       // uint64 prefix[2]
#define S_OUTC   16392       // collected count[2]
#define S_GNNZ   16394       // nonzero-lam count
#define S_GSUM   16395       // float sum(lam)
#define S_WORDS  16396

// ---------------- Threefry-2x32-20 (JAX PRNG) ----------------
#define TF_ROUND(r) { x0 += x1; x1 = (x1 << (r)) | (x1 >> (32 - (r))); x1 ^= x0; }

__host__ __device__ inline void threefry2x32_(uint32_t k0, uint32_t k1,
                                              uint32_t& x0, uint32_t& x1) {
  uint32_t k2 = k0 ^ k1 ^ 0x1BD11BDAu;
  x0 += k0; x1 += k1;
  TF_ROUND(13) TF_ROUND(15) TF_ROUND(26) TF_ROUND(6)
  x0 += k1; x1 += k2 + 1u;
  TF_ROUND(17) TF_ROUND(29) TF_ROUND(16) TF_ROUND(24)
  x0 += k2; x1 += k0 + 2u;
  TF_ROUND(13) TF_ROUND(15) TF_ROUND(26) TF_ROUND(6)
  x0 += k0; x1 += k1 + 3u;
  TF_ROUND(17) TF_ROUND(29) TF_ROUND(16) TF_ROUND(24)
  x0 += k1; x1 += k2 + 4u;
  TF_ROUND(13) TF_ROUND(15) TF_ROUND(26) TF_ROUND(6)
  x0 += k2; x1 += k0 + 5u;
}

// ---------------- init: zero state, set k=2048 ----------------
__global__ __launch_bounds__(256) void k_init(uint32_t* __restrict__ state) {
  uint32_t tid = blockIdx.x * 256 + threadIdx.x;
  if (tid < S_WORDS)
    state[tid] = (tid == S_KK || tid == S_KK + 1) ? NSEL : 0u;
}

// ---------------- G = [W|b]^T [W|b] (5x5) ----------------
__global__ __launch_bounds__(256) void k_G(const float* __restrict__ W,
                                           const float* __restrict__ bfc,
                                           float* __restrict__ Gm) {
  __shared__ float sg[25];
  int t = threadIdx.x;               // one thread per output row (256 rows)
  if (t < 25) sg[t] = 0.f;
  __syncthreads();
  float a[5] = { W[t*4+0], W[t*4+1], W[t*4+2], W[t*4+3], bfc[t] };
  #pragma unroll
  for (int p = 0; p < 5; ++p)
    #pragma unroll
    for (int q = 0; q < 5; ++q)
      atomicAdd(&sg[p*5+q], a[p] * a[q]);
  __syncthreads();
  if (t < 25) Gm[t] = sg[t];
}

// ---------------- masks + threefry scores + candidate append ----------------
__global__ __launch_bounds__(256) void k_mask(
    const float* __restrict__ pfegc, const float* __restrict__ ppre,
    const float* __restrict__ gt,
    uint32_t kp0, uint32_t kp1, uint32_t kn0, uint32_t kn1,
    uint64_t* __restrict__ posKeys, uint64_t* __restrict__ negKeys,
    uint32_t* __restrict__ state) {
  uint32_t i = blockIdx.x * 256 + threadIdx.x;
  if (i >= NPIX) return;
  float pf = pfegc[i];
  if (!(pf >= 0.5f)) return;                       // fegc foreground
  uint32_t hw = i & (HW - 1u);
  uint32_t b  = i >> 18;
  const float* pp = ppre + (size_t)b * 3u * HW + hw;
  float p0 = pp[0], p1 = pp[HW], p2 = pp[2u * HW];
  if (!(p0 >= p1 && p0 >= p2)) return;             // argmax(p_pre)==0
  bool gfg = gt[i] > 0.5f;
  // partitionable threefry random bits: hash of 64-bit index (hi=0, lo=i), fold x0^x1
  uint32_t x0 = 0u, x1 = i;
  if (gfg) threefry2x32_(kp0, kp1, x0, x1);
  else     threefry2x32_(kn0, kn1, x0, x1);
  uint32_t bits = x0 ^ x1;
  // uniform order == (bits>>9) order; tie-break: lower index wins (stable top_k)
  uint64_t key = ((uint64_t)(bits >> 9) << 20) | (uint64_t)(0xFFFFFu ^ i);
  int list = gfg ? 0 : 1;
  uint32_t slot = atomicAdd(&state[S_CNT + list], 1u);
  if (slot < MAXC) (gfg ? posKeys : negKeys)[slot] = key;
  atomicAdd(&state[S_HIST + list * 2048 + (uint32_t)(key >> 33)], 1u); // round-0 hist
}

// ---------------- radix-select: histogram for rounds 1..3 ----------------
__global__ __launch_bounds__(256) void k_hist(
    const uint64_t* __restrict__ posKeys, const uint64_t* __restrict__ negKeys,
    uint32_t* __restrict__ state, int r) {
  int list = blockIdx.y;
  const uint64_t* keys = list ? negKeys : posKeys;
  uint32_t n = state[S_CNT + list]; if (n > MAXC) n = MAXC;
  uint32_t tid = blockIdx.x * 256 + threadIdx.x;
  if (tid >= n) return;
  uint64_t key  = keys[tid];
  uint64_t pref = ((const uint64_t*)(state + S_PREFIX))[list];
  int cs = 44 - 11 * r;                 // condition shift
  if ((key >> cs) != pref) return;
  uint32_t digit = (uint32_t)(key >> (cs - 11)) & 0x7FFu;
  atomicAdd(&state[S_HIST + r * 4096 + list * 2048 + digit], 1u);
}

// ---------------- radix-select: pick digit, descend ----------------
__global__ __launch_bounds__(256) void k_scan(uint32_t* __restrict__ state, int r) {
  __shared__ uint32_t part[256];
  __shared__ int gsel;
  int t = threadIdx.x;
  for (int list = 0; list < 2; ++list) {
    uint32_t* h = state + S_HIST + r * 4096 + list * 2048;
    uint32_t k = state[S_KK + list];
    uint32_t s = 0;
    #pragma unroll
    for (int e = 0; e < 8; ++e) s += h[t * 8 + e];
    part[t] = s;
    __syncthreads();
    // Hillis-Steele suffix scan: part[t] = sum_{u>=t} psum[u]
    for (int off = 1; off < 256; off <<= 1) {
      uint32_t v = part[t];
      uint32_t add = (t + off < 256) ? part[t + off] : 0u;
      __syncthreads();
      part[t] = v + add;
      __syncthreads();
    }
    if (part[t] >= k && (t == 255 || part[t + 1] < k)) gsel = t;
    __syncthreads();
    if (t == 0) {
      int g = gsel;
      uint32_t cum = (g < 255) ? part[g + 1] : 0u;  // keys with digit group > g
      int d = g * 8;
      for (int e = g * 8 + 7; e >= g * 8; --e) {
        uint32_t he = h[e];
        if (cum + he >= k) { d = e; break; }
        cum += he;
      }
      state[S_KK + list] = k - cum;                 // rank within chosen digit
      uint64_t* pref = (uint64_t*)(state + S_PREFIX);
      pref[list] = (pref[list] << 11) | (uint64_t)(uint32_t)d;
    }
    __syncthreads();
  }
}

// ---------------- collect: key >= exact 2048th-largest key ----------------
__global__ __launch_bounds__(256) void k_collect(
    const uint64_t* __restrict__ posKeys, const uint64_t* __restrict__ negKeys,
    uint32_t* __restrict__ state, uint32_t* __restrict__ pos_idx,
    uint32_t* __restrict__ neg_idx) {
  int list = blockIdx.y;
  const uint64_t* keys = list ? negKeys : posKeys;
  uint32_t n = state[S_CNT + list]; if (n > MAXC) n = MAXC;
  uint32_t tid = blockIdx.x * 256 + threadIdx.x;
  if (tid >= n) return;
  uint64_t key = keys[tid];
  uint64_t thr = ((const uint64_t*)(state + S_PREFIX))[list];
  if (key >= thr) {
    uint32_t slot = atomicAdd(&state[S_OUTC + list], 1u);
    if (slot < NSEL)
      (list ? neg_idx : pos_idx)[slot] = 0xFFFFFu ^ (uint32_t)(key & 0xFFFFFu);
  }
}

// ---------------- project to rank-5 form: v = y/|Ay|, w = G v ----------------
__global__ __launch_bounds__(256) void k_project(
    const float* __restrict__ d1, const uint32_t* __restrict__ pos_idx,
    const uint32_t* __restrict__ neg_idx, const float* __restrict__ Gm,
    float* __restrict__ va, float* __restrict__ wa) {
  __shared__ float sG[25];
  if (threadIdx.x < 25) sG[threadIdx.x] = Gm[threadIdx.x];
  __syncthreads();
  uint32_t t = blockIdx.x * 256 + threadIdx.x;
  if (t >= TPTS) return;
  uint32_t idx = (t < NSEL) ? pos_idx[t] : neg_idx[t - NSEL];
  idx &= (NPIX - 1u);
  uint32_t hw = idx & (HW - 1u);
  uint32_t b  = idx >> 18;
  const float* f = d1 + ((size_t)b << 20) + hw;   // b*C*HW, C=4
  float y[5] = { f[0], f[HW], f[2u*HW], f[3u*HW], 1.0f };
  float z[5]; float n2 = 0.f;
  #pragma unroll
  for (int p = 0; p < 5; ++p) {
    float acc = 0.f;
    #pragma unroll
    for (int q = 0; q < 5; ++q) acc += sG[p*5+q] * y[q];
    z[p] = acc; n2 += acc * y[p];                  // = |proj|^2
  }
  n2 = fmaxf(n2, 0.f);
  float nn = fmaxf(sqrtf(n2), 1e-8f);              // eps clamp as reference
  float inv = 1.0f / nn;
  #pragma unroll
  for (int p = 0; p < 5; ++p) { va[t*5+p] = y[p]*inv; wa[t*5+p] = z[p]*inv; }
}

// ---------------- pairwise loss: cos_ij = v_i . w_j (5-dim) ----------------
__global__ __launch_bounds__(256) void k_pair(
    const float* __restrict__ va, const float* __restrict__ wa,
    uint32_t* __restrict__ state) {
  __shared__ float sv[128*5], sw[128*5];
  int i0 = blockIdx.x * 128, j0 = blockIdx.y * 128;
  int t = threadIdx.x;
  for (int u = t; u < 640; u += 256) { sv[u] = va[i0*5 + u]; sw[u] = wa[j0*5 + u]; }
  __syncthreads();
  int ty = t >> 4, tx = t & 15;
  float rv[8][5], rw[8][5];
  #pragma unroll
  for (int a = 0; a < 8; ++a)
    #pragma unroll
    for (int p = 0; p < 5; ++p) {
      rv[a][p] = sv[(ty*8+a)*5 + p];
      rw[a][p] = sw[(tx*8+a)*5 + p];
    }
  float lsum = 0.f; uint32_t lnz = 0;
  #pragma unroll
  for (int a = 0; a < 8; ++a) {
    int gi = i0 + ty*8 + a;
    #pragma unroll
    for (int q = 0; q < 8; ++q) {
      int gj = j0 + tx*8 + q;
      float c = rv[a][0]*rw[q][0] + rv[a][1]*rw[q][1] + rv[a][2]*rw[q][2]
              + rv[a][3]*rw[q][3] + rv[a][4]*rw[q][4];
      float s = c * 10.0f;                          // / TAU
      if (gi != gj) {
        if (((gi ^ gj) & 2048) == 0) {              // same block (pos-pos / neg-neg)
          float m = fmaxf(0.5f - s, 0.f);
          lsum += m * m;
          lnz  += (m > 0.f) ? 1u : 0u;
        } else {                                    // cross block
          lsum += s * s;
          lnz  += (s != 0.f) ? 1u : 0u;
        }
      }
    }
  }
  __shared__ float rs[256];
  __shared__ uint32_t rn[256];
  rs[t] = lsum; rn[t] = lnz;
  __syncthreads();
  for (int off = 128; off > 0; off >>= 1) {
    if (t < off) { rs[t] += rs[t+off]; rn[t] += rn[t+off]; }
    __syncthreads();
  }
  if (t == 0) {
    atomicAdd((float*)(state + S_GSUM), rs[0]);
    atomicAdd(state + S_GNNZ, rn[0]);
  }
}

__global__ void k_final(const uint32_t* __restrict__ state, float* __restrict__ out) {
  out[0] = ((const float*)(state + S_GSUM))[0] / (float)state[S_GNNZ];
}

extern "C" void kernel_launch(void* const* d_in, const int* in_sizes, int n_in,
                              void* d_out, int out_size, void* d_ws, size_t ws_size,
                              hipStream_t stream) {
  (void)in_sizes; (void)n_in; (void)out_size; (void)ws_size;
  const float* d1    = (const float*)d_in[0];
  const float* pfegc = (const float*)d_in[1];
  const float* ppre  = (const float*)d_in[2];
  const float* gt    = (const float*)d_in[3];
  const float* W     = (const float*)d_in[4];
  const float* bfc   = (const float*)d_in[5];
  float* out = (float*)d_out;

  uint8_t* base = (uint8_t*)d_ws;                       // ~2.35 MB used
  uint64_t* posKeys = (uint64_t*)(base);                        // 1 MB
  uint64_t* negKeys = (uint64_t*)(base + (size_t)(1u<<20));     // 1 MB
  float*    va      = (float*)(base + (size_t)(2u<<20));        // 80 KB
  float*    wa      = (float*)(base + (size_t)(2u<<20) + 81920);// 80 KB
  uint32_t* pos_idx = (uint32_t*)(base + (size_t)(2u<<20) + 163840);
  uint32_t* neg_idx = (uint32_t*)(base + (size_t)(2u<<20) + 172032);
  float*    Gm      = (float*)(base + (size_t)(2u<<20) + 180224);
  uint32_t* state   = (uint32_t*)(base + (size_t)(2u<<20) + 180352);

  // key(42) -> [0,42]; partitionable (foldlike) split:
  //   kp = threefry(0,42, hi=0, lo=0), kn = threefry(0,42, hi=0, lo=1)
  uint32_t kp0 = 0u, kp1 = 0u; threefry2x32_(0u, 42u, kp0, kp1);
  uint32_t kn0 = 0u, kn1 = 1u; threefry2x32_(0u, 42u, kn0, kn1);

  k_init<<<(S_WORDS + 255)/256, 256, 0, stream>>>(state);
  k_G<<<1, 256, 0, stream>>>(W, bfc, Gm);
  k_mask<<<NPIX/256, 256, 0, stream>>>(pfegc, ppre, gt, kp0, kp1, kn0, kn1,
                                       posKeys, negKeys, state);
  k_scan<<<1, 256, 0, stream>>>(state, 0);
  for (int r = 1; r <= 3; ++r) {
    k_hist<<<dim3(MAXC/256, 2), 256, 0, stream>>>(posKeys, negKeys, state, r);
    k_scan<<<1, 256, 0, stream>>>(state, r);
  }
  k_collect<<<dim3(MAXC/256, 2), 256, 0, stream>>>(posKeys, negKeys, state,
                                                   pos_idx, neg_idx);
  k_project<<<TPTS/256, 256, 0, stream>>>(d1, pos_idx, neg_idx, Gm, va, wa);
  k_pair<<<dim3(32, 32), 256, 0, stream>>>(va, wa, state);
  k_final<<<1, 1, 0, stream>>>(state, out);
}

// Round 2
// 181.089 us; speedup vs baseline: 8.8508x; 8.8508x over previous
//
#include <hip/hip_runtime.h>
#include <stdint.h>

#define HW      262144u      // 512*512
#define NPIX    1048576u     // 4*HW  (pixel index fits in 20 bits)
#define NSEL    2048u        // POS_NUM*B = NEG_NUM*B
#define TPTS    4096u
#define NB0     1024u        // blocks for mask/compact; 1024 pixels each
#define CANDCAP 8192u

// workspace byte offsets (~6.3 MB total)
#define OFF_AWORD   0u         // u32[NPIX]            4 MB
#define OFF_BLKHIST 4194304u   // u32[512*1024]        2 MB  rows: (list*256+bin)*1024 + blk
#define OFF_GHIST   6291456u   // u32[512]
#define OFF_BLKBASE 6293504u   // u32[2*1024]
#define OFF_CTRL    6301696u   // u32: d0[2], candcnt[2]
#define OFF_CAND    6301952u   // u64[2*8192]          128 KB
#define OFF_IDX     6433024u   // u32[4096]  pos then neg
#define OFF_GM      6449408u   // f32[25]
#define OFF_VA      6449536u   // f32[4096*5]
#define OFF_WA      6531456u   // f32[4096*5]
#define OFF_PSUM    6613376u   // f32[1024]
#define OFF_PNNZ    6617472u   // u32[1024]

// ---------------- Threefry-2x32-20 (JAX partitionable PRNG) ----------------
#define TF_ROUND(r) { x0 += x1; x1 = (x1 << (r)) | (x1 >> (32 - (r))); x1 ^= x0; }
__host__ __device__ inline void threefry2x32_(uint32_t k0, uint32_t k1,
                                              uint32_t& x0, uint32_t& x1) {
  uint32_t k2 = k0 ^ k1 ^ 0x1BD11BDAu;
  x0 += k0; x1 += k1;
  TF_ROUND(13) TF_ROUND(15) TF_ROUND(26) TF_ROUND(6)
  x0 += k1; x1 += k2 + 1u;
  TF_ROUND(17) TF_ROUND(29) TF_ROUND(16) TF_ROUND(24)
  x0 += k2; x1 += k0 + 2u;
  TF_ROUND(13) TF_ROUND(15) TF_ROUND(26) TF_ROUND(6)
  x0 += k0; x1 += k1 + 3u;
  TF_ROUND(17) TF_ROUND(29) TF_ROUND(16) TF_ROUND(24)
  x0 += k1; x1 += k2 + 4u;
  TF_ROUND(13) TF_ROUND(15) TF_ROUND(26) TF_ROUND(6)
  x0 += k2; x1 += k0 + 5u;
}

// ---------------- G = [W|b]^T [W|b] (5x5) ----------------
__global__ __launch_bounds__(256) void k_G(const float* __restrict__ W,
                                           const float* __restrict__ bfc,
                                           float* __restrict__ Gm) {
  __shared__ float sg[25];
  int t = threadIdx.x;
  if (t < 25) sg[t] = 0.f;
  __syncthreads();
  float a[5] = { W[t*4+0], W[t*4+1], W[t*4+2], W[t*4+3], bfc[t] };
  #pragma unroll
  for (int p = 0; p < 5; ++p)
    #pragma unroll
    for (int q = 0; q < 5; ++q)
      atomicAdd(&sg[p*5+q], a[p] * a[q]);   // LDS atomics: cheap
  __syncthreads();
  if (t < 25) Gm[t] = sg[t];
}

// ---------------- mask + PRNG scatter + per-block 256-bin hist ----------------
// word: bit31 = valid, bit30 = list (0=pos,1=neg), bits22..0 = (threefry_bits>>9)
__global__ __launch_bounds__(256) void k_maskhist(
    const float* __restrict__ pfegc, const float* __restrict__ ppre,
    const float* __restrict__ gt,
    uint32_t kp0, uint32_t kp1, uint32_t kn0, uint32_t kn1,
    uint32_t* __restrict__ aWord, uint32_t* __restrict__ blkhist) {
  __shared__ uint32_t h[2][256];
  int t = threadIdx.x;
  h[0][t] = 0; h[1][t] = 0;
  __syncthreads();
  uint32_t b = blockIdx.x;
  #pragma unroll
  for (int j = 0; j < 4; ++j) {
    uint32_t i = b * 1024u + (uint32_t)j * 256u + (uint32_t)t;
    uint32_t w = 0u;
    float pf = pfegc[i];
    if (pf >= 0.5f) {
      uint32_t hw = i & (HW - 1u);
      uint32_t bb = i >> 18;
      const float* pp = ppre + (size_t)bb * 3u * HW + hw;
      float p0 = pp[0], p1 = pp[HW], p2 = pp[2u * HW];
      if (p0 >= p1 && p0 >= p2) {
        bool gfg = gt[i] > 0.5f;
        uint32_t kk0 = gfg ? kp0 : kn0, kk1 = gfg ? kp1 : kn1;
        uint32_t x0 = 0u, x1 = i;
        threefry2x32_(kk0, kk1, x0, x1);
        uint32_t r23 = (x0 ^ x1) >> 9;
        uint32_t list = gfg ? 0u : 1u;
        w = 0x80000000u | (list << 30) | r23;
        atomicAdd(&h[list][128u + (r23 >> 16)], 1u);   // LDS atomic
      }
    }
    aWord[i] = w;
  }
  __syncthreads();
  blkhist[(uint32_t)t * 1024u + b]          = h[0][t];
  blkhist[(256u + (uint32_t)t) * 1024u + b] = h[1][t];
}

// ---------------- reduce blkhist rows -> ghist[512] (1 wave/row) ----------------
__global__ __launch_bounds__(256) void k_reduce(const uint32_t* __restrict__ blkhist,
                                                uint32_t* __restrict__ ghist) {
  int t = threadIdx.x;
  uint32_t row = blockIdx.x * 4u + ((uint32_t)t >> 6);
  uint32_t lane = (uint32_t)t & 63u;
  uint32_t sum = 0;
  #pragma unroll
  for (int it = 0; it < 16; ++it)
    sum += blkhist[row * 1024u + (uint32_t)it * 64u + lane];
  #pragma unroll
  for (int off = 32; off > 0; off >>= 1)
    sum += (uint32_t)__shfl_down((int)sum, off, 64);
  if (lane == 0) ghist[row] = sum;
}

// ---------------- scan: pick d0, build deterministic per-block bases ----------------
__global__ __launch_bounds__(256) void k_scan0(const uint32_t* __restrict__ ghist,
                                               const uint32_t* __restrict__ blkhist,
                                               uint32_t* __restrict__ blkbase,
                                               uint32_t* __restrict__ ctrl) {
  __shared__ uint32_t suf[256];
  __shared__ uint32_t cb[256];
  __shared__ int gd0;
  int t = threadIdx.x;
  for (int list = 0; list < 2; ++list) {
    if (t == 0) gd0 = 0;
    uint32_t v = ghist[list * 256 + t];
    suf[t] = v;
    __syncthreads();
    for (int off = 1; off < 256; off <<= 1) {
      uint32_t x = suf[t];
      uint32_t y = (t + off < 256) ? suf[t + off] : 0u;
      __syncthreads();
      suf[t] = x + y;
      __syncthreads();
    }
    if (suf[t] >= NSEL && (t == 255 || suf[t + 1] < NSEL)) gd0 = t;
    __syncthreads();
    int d0 = gd0;
    if (t == 0) ctrl[list] = (uint32_t)d0;
    // per-block member counts: thread t owns blocks 4t..4t+3
    uint32_t c0 = 0, c1 = 0, c2 = 0, c3 = 0;
    for (int bin = d0; bin < 256; ++bin) {
      const uint32_t* rowp = blkhist + ((uint32_t)list * 256u + (uint32_t)bin) * 1024u;
      c0 += rowp[4 * t + 0]; c1 += rowp[4 * t + 1];
      c2 += rowp[4 * t + 2]; c3 += rowp[4 * t + 3];
    }
    uint32_t s = c0 + c1 + c2 + c3;
    cb[t] = s;
    __syncthreads();
    for (int off = 1; off < 256; off <<= 1) {
      uint32_t x = cb[t];
      uint32_t add = (t >= off) ? cb[t - off] : 0u;
      __syncthreads();
      cb[t] = x + add;
      __syncthreads();
    }
    uint32_t base = cb[t] - s;                  // exclusive prefix
    blkbase[list * 1024 + 4 * t + 0] = base;
    blkbase[list * 1024 + 4 * t + 1] = base + c0;
    blkbase[list * 1024 + 4 * t + 2] = base + c0 + c1;
    blkbase[list * 1024 + 4 * t + 3] = base + c0 + c1 + c2;
    if (t == 255) ctrl[2 + list] = cb[255];     // candcnt
    __syncthreads();
  }
}

// ---------------- compact keys with digit >= d0 into cand (LDS ranks only) ----------------
__global__ __launch_bounds__(256) void k_compact(
    const uint32_t* __restrict__ aWord, const uint32_t* __restrict__ ctrl,
    const uint32_t* __restrict__ blkbase, uint64_t* __restrict__ cand) {
  __shared__ uint32_t lc[2];
  __shared__ uint32_t sd0[2];
  __shared__ uint32_t lbase[2];
  int t = threadIdx.x;
  uint32_t b = blockIdx.x;
  if (t < 2) { lc[t] = 0; sd0[t] = ctrl[t]; lbase[t] = blkbase[(uint32_t)t * 1024u + b]; }
  __syncthreads();
  #pragma unroll
  for (int j = 0; j < 4; ++j) {
    uint32_t i = b * 1024u + (uint32_t)j * 256u + (uint32_t)t;
    uint32_t w = aWord[i];
    if (w & 0x80000000u) {
      uint32_t list = (w >> 30) & 1u;
      uint32_t r23 = w & 0x7FFFFFu;
      uint32_t digit = 128u + (r23 >> 16);
      if (digit >= sd0[list]) {
        uint32_t r = atomicAdd(&lc[list], 1u);  // LDS atomic
        uint32_t slot = lbase[list] + r;
        if (slot < CANDCAP)
          cand[(size_t)list * CANDCAP + slot] =
              (1ull << 43) | ((uint64_t)r23 << 20) | (uint64_t)(0xFFFFFu ^ i);
      }
    }
  }
}

// ---------------- exact top-2048 select within cand (1 block/list) ----------------
__global__ __launch_bounds__(256) void k_small(
    const uint64_t* __restrict__ cand, const uint32_t* __restrict__ ctrl,
    uint32_t* __restrict__ idxbuf) {
  __shared__ uint32_t hist[2048];
  __shared__ uint32_t part[256];
  __shared__ int gsel;
  __shared__ uint64_t spref;
  __shared__ uint32_t skk;
  __shared__ uint32_t rank;
  int t = threadIdx.x;
  int list = blockIdx.x;
  uint32_t n = ctrl[2 + list]; if (n > CANDCAP) n = CANDCAP;
  const uint64_t* ck = cand + (size_t)list * CANDCAP;
  if (t == 0) { spref = 0ull; skk = NSEL; rank = 0; }
  for (int r = 0; r < 4; ++r) {
    #pragma unroll
    for (int e = 0; e < 8; ++e) hist[t * 8 + e] = 0;
    __syncthreads();
    int csp = 44 - 11 * r;      // parent-prefix shift
    int cs = csp - 11;          // digit shift
    uint64_t pref = spref;
    for (uint32_t j = t; j < n; j += 256) {
      uint64_t key = ck[j];
      if ((key >> csp) == pref)
        atomicAdd(&hist[(uint32_t)(key >> cs) & 0x7FFu], 1u);
    }
    __syncthreads();
    uint32_t s = 0;
    #pragma unroll
    for (int e = 0; e < 8; ++e) s += hist[t * 8 + e];
    part[t] = s;
    __syncthreads();
    for (int off = 1; off < 256; off <<= 1) {
      uint32_t x = part[t];
      uint32_t y = (t + off < 256) ? part[t + off] : 0u;
      __syncthreads();
      part[t] = x + y;
      __syncthreads();
    }
    uint32_t k = skk;
    if (part[t] >= k && (t == 255 || part[t + 1] < k)) gsel = t;
    __syncthreads();
    if (t == 0) {
      int g = gsel;
      uint32_t cum = (g < 255) ? part[g + 1] : 0u;
      int d = g * 8;
      for (int e = g * 8 + 7; e >= g * 8; --e) {
        uint32_t he = hist[e];
        if (cum + he >= k) { d = e; break; }
        cum += he;
      }
      skk = k - cum;
      spref = (pref << 11) | (uint64_t)(uint32_t)d;
    }
    __syncthreads();
  }
  uint64_t thr = spref;
  for (uint32_t j = t; j < n; j += 256) {
    uint64_t key = ck[j];
    if (key >= thr) {
      uint32_t rr = atomicAdd(&rank, 1u);      // LDS atomic
      if (rr < NSEL)
        idxbuf[(uint32_t)list * NSEL + rr] = 0xFFFFFu ^ (uint32_t)(key & 0xFFFFFu);
    }
  }
}

// ---------------- project to rank-5 form: v = y/|proj|, w = G v ----------------
__global__ __launch_bounds__(256) void k_project(
    const float* __restrict__ d1, const uint32_t* __restrict__ idxbuf,
    const float* __restrict__ Gm, float* __restrict__ va, float* __restrict__ wa) {
  __shared__ float sG[25];
  if (threadIdx.x < 25) sG[threadIdx.x] = Gm[threadIdx.x];
  __syncthreads();
  uint32_t t = blockIdx.x * 256 + threadIdx.x;
  if (t >= TPTS) return;
  uint32_t idx = idxbuf[t] & (NPIX - 1u);
  uint32_t hw = idx & (HW - 1u);
  uint32_t b = idx >> 18;
  const float* f = d1 + ((size_t)b << 20) + hw;
  float y[5] = { f[0], f[HW], f[2u * HW], f[3u * HW], 1.0f };
  float z[5]; float n2 = 0.f;
  #pragma unroll
  for (int p = 0; p < 5; ++p) {
    float acc = 0.f;
    #pragma unroll
    for (int q = 0; q < 5; ++q) acc += sG[p * 5 + q] * y[q];
    z[p] = acc; n2 += acc * y[p];
  }
  n2 = fmaxf(n2, 0.f);
  float nn = fmaxf(sqrtf(n2), 1e-8f);
  float inv = 1.0f / nn;
  #pragma unroll
  for (int p = 0; p < 5; ++p) { va[t * 5 + p] = y[p] * inv; wa[t * 5 + p] = z[p] * inv; }
}

// ---------------- pairwise loss: per-block partials, no global atomics ----------------
__global__ __launch_bounds__(256) void k_pair(
    const float* __restrict__ va, const float* __restrict__ wa,
    float* __restrict__ psum, uint32_t* __restrict__ pnnz) {
  __shared__ float sv[128 * 5], sw[128 * 5];
  int i0 = blockIdx.x * 128, j0 = blockIdx.y * 128;
  int t = threadIdx.x;
  for (int u = t; u < 640; u += 256) { sv[u] = va[i0 * 5 + u]; sw[u] = wa[j0 * 5 + u]; }
  __syncthreads();
  int ty = t >> 4, tx = t & 15;
  float rv[8][5], rw[8][5];
  #pragma unroll
  for (int a = 0; a < 8; ++a)
    #pragma unroll
    for (int p = 0; p < 5; ++p) {
      rv[a][p] = sv[(ty * 8 + a) * 5 + p];
      rw[a][p] = sw[(tx * 8 + a) * 5 + p];
    }
  float lsum = 0.f; uint32_t lnz = 0;
  #pragma unroll
  for (int a = 0; a < 8; ++a) {
    int gi = i0 + ty * 8 + a;
    #pragma unroll
    for (int q = 0; q < 8; ++q) {
      int gj = j0 + tx * 8 + q;
      float c = rv[a][0]*rw[q][0] + rv[a][1]*rw[q][1] + rv[a][2]*rw[q][2]
              + rv[a][3]*rw[q][3] + rv[a][4]*rw[q][4];
      float s = c * 10.0f;                     // / TAU
      if (gi != gj) {
        if (((gi ^ gj) & 2048) == 0) {         // same block
          float m = fmaxf(0.5f - s, 0.f);
          lsum += m * m;
          lnz += (m > 0.f) ? 1u : 0u;
        } else {                               // cross block
          lsum += s * s;
          lnz += (s != 0.f) ? 1u : 0u;
        }
      }
    }
  }
  __shared__ float rs[256];
  __shared__ uint32_t rn[256];
  rs[t] = lsum; rn[t] = lnz;
  __syncthreads();
  for (int off = 128; off > 0; off >>= 1) {
    if (t < off) { rs[t] += rs[t + off]; rn[t] += rn[t + off]; }
    __syncthreads();
  }
  if (t == 0) {
    int bid = blockIdx.y * gridDim.x + blockIdx.x;
    psum[bid] = rs[0];
    pnnz[bid] = rn[0];
  }
}

__global__ __launch_bounds__(256) void k_final(const float* __restrict__ psum,
                                               const uint32_t* __restrict__ pnnz,
                                               float* __restrict__ out) {
  __shared__ float rs[256];
  __shared__ uint32_t rn[256];
  int t = threadIdx.x;
  float s = 0.f; uint32_t nz = 0;
  for (int j = t; j < 1024; j += 256) { s += psum[j]; nz += pnnz[j]; }
  rs[t] = s; rn[t] = nz;
  __syncthreads();
  for (int off = 128; off > 0; off >>= 1) {
    if (t < off) { rs[t] += rs[t + off]; rn[t] += rn[t + off]; }
    __syncthreads();
  }
  if (t == 0) out[0] = rs[0] / (float)rn[0];
}

extern "C" void kernel_launch(void* const* d_in, const int* in_sizes, int n_in,
                              void* d_out, int out_size, void* d_ws, size_t ws_size,
                              hipStream_t stream) {
  (void)in_sizes; (void)n_in; (void)out_size; (void)ws_size;
  const float* d1    = (const float*)d_in[0];
  const float* pfegc = (const float*)d_in[1];
  const float* ppre  = (const float*)d_in[2];
  const float* gt    = (const float*)d_in[3];
  const float* W     = (const float*)d_in[4];
  const float* bfc   = (const float*)d_in[5];
  float* out = (float*)d_out;

  uint8_t* base = (uint8_t*)d_ws;
  uint32_t* aWord   = (uint32_t*)(base + OFF_AWORD);
  uint32_t* blkhist = (uint32_t*)(base + OFF_BLKHIST);
  uint32_t* ghist   = (uint32_t*)(base + OFF_GHIST);
  uint32_t* blkbase = (uint32_t*)(base + OFF_BLKBASE);
  uint32_t* ctrl    = (uint32_t*)(base + OFF_CTRL);
  uint64_t* cand    = (uint64_t*)(base + OFF_CAND);
  uint32_t* idxbuf  = (uint32_t*)(base + OFF_IDX);
  float*    Gm      = (float*)(base + OFF_GM);
  float*    va      = (float*)(base + OFF_VA);
  float*    wa      = (float*)(base + OFF_WA);
  float*    psum    = (float*)(base + OFF_PSUM);
  uint32_t* pnnz    = (uint32_t*)(base + OFF_PNNZ);

  // jax.random.key(42), partitionable split: kp = tf(0,42,{0,0}), kn = tf(0,42,{0,1})
  uint32_t kp0 = 0u, kp1 = 0u; threefry2x32_(0u, 42u, kp0, kp1);
  uint32_t kn0 = 0u, kn1 = 1u; threefry2x32_(0u, 42u, kn0, kn1);

  k_G<<<1, 256, 0, stream>>>(W, bfc, Gm);
  k_maskhist<<<NB0, 256, 0, stream>>>(pfegc, ppre, gt, kp0, kp1, kn0, kn1,
                                      aWord, blkhist);
  k_reduce<<<128, 256, 0, stream>>>(blkhist, ghist);
  k_scan0<<<1, 256, 0, stream>>>(ghist, blkhist, blkbase, ctrl);
  k_compact<<<NB0, 256, 0, stream>>>(aWord, ctrl, blkbase, cand);
  k_small<<<2, 256, 0, stream>>>(cand, ctrl, idxbuf);
  k_project<<<TPTS / 256, 256, 0, stream>>>(d1, idxbuf, Gm, va, wa);
  k_pair<<<dim3(32, 32), 256, 0, stream>>>(va, wa, psum, pnnz);
  k_final<<<1, 256, 0, stream>>>(psum, pnnz, out);
}

// Round 3
// 138.801 us; speedup vs baseline: 11.5473x; 1.3047x over previous
//
#include <hip/hip_runtime.h>
#include <stdint.h>

#define HW      262144u      // 512*512
#define NPIX    1048576u     // 4*HW (pixel index fits in 20 bits)
#define NSEL    2048u        // POS_NUM*B = NEG_NUM*B
#define TPTS    4096u
#define NB0     1024u        // blocks for mask/compact; 1024 pixels each
#define CANDCAP 8192u

// workspace byte offsets (~6.6 MB total)
#define OFF_AWORD   0u         // u32[NPIX]            4 MB
#define OFF_BLKHIST 4194304u   // u32[512*1024]        2 MB  rows: (list*256+bin)*1024 + blk
#define OFF_GHIST   6291456u   // u32[512]
#define OFF_BLKBASE 6293504u   // u32[2*1024]
#define OFF_CTRL    6301696u   // u32: d0[2], candcnt[2]
#define OFF_CAND    6301952u   // u64[2*8192]          128 KB
#define OFF_VA      6449536u   // f32[4096*5]
#define OFF_WA      6531456u   // f32[4096*5]
#define OFF_PSUM    6613376u   // f32[1024]
#define OFF_PNNZ    6617472u   // u32[1024]

// ---------------- Threefry-2x32-20 (JAX partitionable PRNG) ----------------
#define TF_ROUND(r) { x0 += x1; x1 = (x1 << (r)) | (x1 >> (32 - (r))); x1 ^= x0; }
__host__ __device__ inline void threefry2x32_(uint32_t k0, uint32_t k1,
                                              uint32_t& x0, uint32_t& x1) {
  uint32_t k2 = k0 ^ k1 ^ 0x1BD11BDAu;
  x0 += k0; x1 += k1;
  TF_ROUND(13) TF_ROUND(15) TF_ROUND(26) TF_ROUND(6)
  x0 += k1; x1 += k2 + 1u;
  TF_ROUND(17) TF_ROUND(29) TF_ROUND(16) TF_ROUND(24)
  x0 += k2; x1 += k0 + 2u;
  TF_ROUND(13) TF_ROUND(15) TF_ROUND(26) TF_ROUND(6)
  x0 += k0; x1 += k1 + 3u;
  TF_ROUND(17) TF_ROUND(29) TF_ROUND(16) TF_ROUND(24)
  x0 += k1; x1 += k2 + 4u;
  TF_ROUND(13) TF_ROUND(15) TF_ROUND(26) TF_ROUND(6)
  x0 += k2; x1 += k0 + 5u;
}

// ---------------- mask + PRNG scatter + per-block 256-bin hist ----------------
// word: bit31 = valid, bit30 = list (0=pos,1=neg), bits22..0 = (threefry_bits>>9)
__global__ __launch_bounds__(256) void k_maskhist(
    const float* __restrict__ pfegc, const float* __restrict__ ppre,
    const float* __restrict__ gt,
    uint32_t kp0, uint32_t kp1, uint32_t kn0, uint32_t kn1,
    uint32_t* __restrict__ aWord, uint32_t* __restrict__ blkhist) {
  __shared__ uint32_t h[2][256];
  int t = threadIdx.x;
  h[0][t] = 0; h[1][t] = 0;
  __syncthreads();
  uint32_t b = blockIdx.x;
  uint32_t base = b * 1024u + (uint32_t)t * 4u;
  float4 pf = *(const float4*)(pfegc + base);
  float pfa[4] = { pf.x, pf.y, pf.z, pf.w };
  uint32_t wv[4] = { 0u, 0u, 0u, 0u };
  bool any = (pf.x >= 0.5f) || (pf.y >= 0.5f) || (pf.z >= 0.5f) || (pf.w >= 0.5f);
  if (any) {
    uint32_t hw = base & (HW - 1u);
    uint32_t bb = base >> 18;                 // base..base+3 share the image
    const float* pp = ppre + (size_t)bb * 3u * HW + hw;
    float4 p0 = *(const float4*)pp;
    float4 p1 = *(const float4*)(pp + HW);
    float4 p2 = *(const float4*)(pp + 2u * HW);
    float4 g4 = *(const float4*)(gt + base);
    float p0a[4] = { p0.x, p0.y, p0.z, p0.w };
    float p1a[4] = { p1.x, p1.y, p1.z, p1.w };
    float p2a[4] = { p2.x, p2.y, p2.z, p2.w };
    float ga[4]  = { g4.x, g4.y, g4.z, g4.w };
    #pragma unroll
    for (int j = 0; j < 4; ++j) {
      if (pfa[j] >= 0.5f && p0a[j] >= p1a[j] && p0a[j] >= p2a[j]) {
        uint32_t i = base + (uint32_t)j;
        bool gfg = ga[j] > 0.5f;
        uint32_t x0 = 0u, x1 = i;
        threefry2x32_(gfg ? kp0 : kn0, gfg ? kp1 : kn1, x0, x1);
        uint32_t r23 = (x0 ^ x1) >> 9;
        uint32_t list = gfg ? 0u : 1u;
        wv[j] = 0x80000000u | (list << 30) | r23;
        atomicAdd(&h[list][128u + (r23 >> 16)], 1u);   // u32 LDS atomic, 256 bins
      }
    }
  }
  uint4 outw = make_uint4(wv[0], wv[1], wv[2], wv[3]);
  *(uint4*)(aWord + base) = outw;
  __syncthreads();
  blkhist[(uint32_t)t * 1024u + b]          = h[0][t];
  blkhist[(256u + (uint32_t)t) * 1024u + b] = h[1][t];
}

// ---------------- reduce blkhist rows -> ghist[512] (1 wave/row) ----------------
__global__ __launch_bounds__(256) void k_reduce(const uint32_t* __restrict__ blkhist,
                                                uint32_t* __restrict__ ghist) {
  int t = threadIdx.x;
  uint32_t row = blockIdx.x * 4u + ((uint32_t)t >> 6);
  uint32_t lane = (uint32_t)t & 63u;
  uint32_t sum = 0;
  #pragma unroll
  for (int it = 0; it < 4; ++it) {
    uint4 v = *(const uint4*)(blkhist + row * 1024u + ((uint32_t)it * 64u + lane) * 4u);
    sum += v.x + v.y + v.z + v.w;
  }
  #pragma unroll
  for (int off = 32; off > 0; off >>= 1)
    sum += (uint32_t)__shfl_down((int)sum, off, 64);
  if (lane == 0) ghist[row] = sum;
}

// ---------------- scan: pick d0, build deterministic per-block bases ----------------
__global__ __launch_bounds__(256) void k_scan0(const uint32_t* __restrict__ ghist,
                                               const uint32_t* __restrict__ blkhist,
                                               uint32_t* __restrict__ blkbase,
                                               uint32_t* __restrict__ ctrl) {
  __shared__ uint32_t suf[256];
  __shared__ uint32_t cb[256];
  __shared__ int gd0;
  int t = threadIdx.x;
  for (int list = 0; list < 2; ++list) {
    if (t == 0) gd0 = 0;
    uint32_t v = ghist[list * 256 + t];
    suf[t] = v;
    __syncthreads();
    for (int off = 1; off < 256; off <<= 1) {
      uint32_t x = suf[t];
      uint32_t y = (t + off < 256) ? suf[t + off] : 0u;
      __syncthreads();
      suf[t] = x + y;
      __syncthreads();
    }
    if (suf[t] >= NSEL && (t == 255 || suf[t + 1] < NSEL)) gd0 = t;
    __syncthreads();
    int d0 = gd0;
    if (t == 0) ctrl[list] = (uint32_t)d0;
    uint32_t c0 = 0, c1 = 0, c2 = 0, c3 = 0;
    for (int bin = d0; bin < 256; ++bin) {
      const uint32_t* rowp = blkhist + ((uint32_t)list * 256u + (uint32_t)bin) * 1024u;
      c0 += rowp[4 * t + 0]; c1 += rowp[4 * t + 1];
      c2 += rowp[4 * t + 2]; c3 += rowp[4 * t + 3];
    }
    uint32_t s = c0 + c1 + c2 + c3;
    cb[t] = s;
    __syncthreads();
    for (int off = 1; off < 256; off <<= 1) {
      uint32_t x = cb[t];
      uint32_t add = (t >= off) ? cb[t - off] : 0u;
      __syncthreads();
      cb[t] = x + add;
      __syncthreads();
    }
    uint32_t base = cb[t] - s;                  // exclusive prefix
    blkbase[list * 1024 + 4 * t + 0] = base;
    blkbase[list * 1024 + 4 * t + 1] = base + c0;
    blkbase[list * 1024 + 4 * t + 2] = base + c0 + c1;
    blkbase[list * 1024 + 4 * t + 3] = base + c0 + c1 + c2;
    if (t == 255) ctrl[2 + list] = cb[255];     // candcnt
    __syncthreads();
  }
}

// ---------------- compact keys with digit >= d0 into cand (LDS ranks only) ----------------
__global__ __launch_bounds__(256) void k_compact(
    const uint32_t* __restrict__ aWord, const uint32_t* __restrict__ ctrl,
    const uint32_t* __restrict__ blkbase, uint64_t* __restrict__ cand) {
  __shared__ uint32_t lc[2];
  __shared__ uint32_t sd0[2];
  __shared__ uint32_t lbase[2];
  int t = threadIdx.x;
  uint32_t b = blockIdx.x;
  if (t < 2) { lc[t] = 0; sd0[t] = ctrl[t]; lbase[t] = blkbase[(uint32_t)t * 1024u + b]; }
  __syncthreads();
  uint32_t base = b * 1024u + (uint32_t)t * 4u;
  uint4 w4 = *(const uint4*)(aWord + base);
  uint32_t wa4[4] = { w4.x, w4.y, w4.z, w4.w };
  #pragma unroll
  for (int j = 0; j < 4; ++j) {
    uint32_t w = wa4[j];
    if (w & 0x80000000u) {
      uint32_t list = (w >> 30) & 1u;
      uint32_t r23 = w & 0x7FFFFFu;
      uint32_t digit = 128u + (r23 >> 16);
      if (digit >= sd0[list]) {
        uint32_t r = atomicAdd(&lc[list], 1u);          // u32 LDS atomic
        uint32_t slot = lbase[list] + r;
        if (slot < CANDCAP)
          cand[(size_t)list * CANDCAP + slot] =
              (1ull << 43) | ((uint64_t)r23 << 20) | (uint64_t)(0xFFFFFu ^ (base + (uint32_t)j));
      }
    }
  }
}

// ---------------- select top-2048 + project (fused; 1 block/list) ----------------
__global__ __launch_bounds__(256) void k_selproj(
    const uint64_t* __restrict__ cand, const uint32_t* __restrict__ ctrl,
    const float* __restrict__ Wm, const float* __restrict__ bfc,
    const float* __restrict__ d1,
    float* __restrict__ va, float* __restrict__ wa) {
  __shared__ uint32_t hist[2048];
  __shared__ uint32_t part[256];
  __shared__ int gsel;
  __shared__ uint64_t spref;
  __shared__ uint32_t skk;
  __shared__ uint32_t rank;
  __shared__ float sG[25];
  __shared__ float sGw[4][25];
  int t = threadIdx.x;
  int list = blockIdx.x;
  // ---- G = [W|b]^T [W|b] via shuffle reduction (no atomics) ----
  {
    float4 wr = *(const float4*)(Wm + t * 4);
    float av[5] = { wr.x, wr.y, wr.z, wr.w, bfc[t] };
    int lane = t & 63, wvi = t >> 6;
    #pragma unroll
    for (int p = 0; p < 5; ++p)
      #pragma unroll
      for (int q = p; q < 5; ++q) {
        float g = av[p] * av[q];
        #pragma unroll
        for (int off = 32; off > 0; off >>= 1)
          g += __shfl_xor(g, off, 64);
        if (lane == 0) sGw[wvi][p * 5 + q] = g;
      }
  }
  if (t == 0) { spref = 0ull; skk = NSEL; rank = 0; }
  __syncthreads();
  if (t < 25) {
    int p = t / 5, q = t % 5;
    int pp = p < q ? p : q, qq = p < q ? q : p;
    sG[t] = sGw[0][pp * 5 + qq] + sGw[1][pp * 5 + qq]
          + sGw[2][pp * 5 + qq] + sGw[3][pp * 5 + qq];
  }
  uint32_t n = ctrl[2 + list]; if (n > CANDCAP) n = CANDCAP;
  const uint64_t* ck = cand + (size_t)list * CANDCAP;
  __syncthreads();
  // ---- 4-round 11-bit radix select of the exact 2048th-largest key ----
  for (int r = 0; r < 4; ++r) {
    #pragma unroll
    for (int e = 0; e < 8; ++e) hist[t * 8 + e] = 0;
    __syncthreads();
    int csp = 44 - 11 * r;
    int cs = csp - 11;
    uint64_t pref = spref;
    for (uint32_t j = t; j < n; j += 256) {
      uint64_t key = ck[j];
      if ((key >> csp) == pref)
        atomicAdd(&hist[(uint32_t)(key >> cs) & 0x7FFu], 1u);
    }
    __syncthreads();
    uint32_t s = 0;
    #pragma unroll
    for (int e = 0; e < 8; ++e) s += hist[t * 8 + e];
    part[t] = s;
    __syncthreads();
    for (int off = 1; off < 256; off <<= 1) {
      uint32_t x = part[t];
      uint32_t y = (t + off < 256) ? part[t + off] : 0u;
      __syncthreads();
      part[t] = x + y;
      __syncthreads();
    }
    uint32_t k = skk;
    if (part[t] >= k && (t == 255 || part[t + 1] < k)) gsel = t;
    __syncthreads();
    if (t == 0) {
      int g = gsel;
      uint32_t cum = (g < 255) ? part[g + 1] : 0u;
      int d = g * 8;
      for (int e = g * 8 + 7; e >= g * 8; --e) {
        uint32_t he = hist[e];
        if (cum + he >= k) { d = e; break; }
        cum += he;
      }
      skk = k - cum;
      spref = (pref << 11) | (uint64_t)(uint32_t)d;
    }
    __syncthreads();
  }
  // ---- collect survivors and project: v = y/|proj|, w = G v ----
  uint64_t thr = spref;
  for (uint32_t j = t; j < n; j += 256) {
    uint64_t key = ck[j];
    if (key >= thr) {
      uint32_t rr = atomicAdd(&rank, 1u);                // u32 LDS atomic
      if (rr < NSEL) {
        uint32_t idx = 0xFFFFFu ^ (uint32_t)(key & 0xFFFFFu);
        uint32_t hw = idx & (HW - 1u);
        uint32_t bb = idx >> 18;
        const float* f = d1 + ((size_t)bb << 20) + hw;
        float y[5] = { f[0], f[HW], f[2u * HW], f[3u * HW], 1.0f };
        float z[5]; float n2 = 0.f;
        #pragma unroll
        for (int p = 0; p < 5; ++p) {
          float acc = 0.f;
          #pragma unroll
          for (int q = 0; q < 5; ++q) acc += sG[p * 5 + q] * y[q];
          z[p] = acc; n2 += acc * y[p];                  // = |proj|^2
        }
        n2 = fmaxf(n2, 0.f);
        float inv = 1.0f / fmaxf(sqrtf(n2), 1e-8f);
        uint32_t s5 = ((uint32_t)list * NSEL + rr) * 5u;
        #pragma unroll
        for (int p = 0; p < 5; ++p) {
          va[s5 + p] = y[p] * inv;
          wa[s5 + p] = z[p] * inv;
        }
      }
    }
  }
}

// ---------------- pairwise loss: per-block partials, no global atomics ----------------
__global__ __launch_bounds__(256) void k_pair(
    const float* __restrict__ va, const float* __restrict__ wa,
    float* __restrict__ psum, uint32_t* __restrict__ pnnz) {
  __shared__ float sv[128 * 5], sw[128 * 5];
  int i0 = blockIdx.x * 128, j0 = blockIdx.y * 128;
  int t = threadIdx.x;
  for (int u = t; u < 640; u += 256) { sv[u] = va[i0 * 5 + u]; sw[u] = wa[j0 * 5 + u]; }
  __syncthreads();
  int ty = t >> 4, tx = t & 15;
  float rv[8][5], rw[8][5];
  #pragma unroll
  for (int a = 0; a < 8; ++a)
    #pragma unroll
    for (int p = 0; p < 5; ++p) {
      rv[a][p] = sv[(ty * 8 + a) * 5 + p];
      rw[a][p] = sw[(tx * 8 + a) * 5 + p];
    }
  float lsum = 0.f; uint32_t lnz = 0;
  #pragma unroll
  for (int a = 0; a < 8; ++a) {
    int gi = i0 + ty * 8 + a;
    #pragma unroll
    for (int q = 0; q < 8; ++q) {
      int gj = j0 + tx * 8 + q;
      float c = rv[a][0]*rw[q][0] + rv[a][1]*rw[q][1] + rv[a][2]*rw[q][2]
              + rv[a][3]*rw[q][3] + rv[a][4]*rw[q][4];
      float s = c * 10.0f;                     // / TAU
      if (gi != gj) {
        if (((gi ^ gj) & 2048) == 0) {         // same block (pos-pos / neg-neg)
          float m = fmaxf(0.5f - s, 0.f);
          lsum += m * m;
          lnz += (m > 0.f) ? 1u : 0u;
        } else {                               // cross block
          lsum += s * s;
          lnz += (s != 0.f) ? 1u : 0u;
        }
      }
    }
  }
  __shared__ float rs[256];
  __shared__ uint32_t rn[256];
  rs[t] = lsum; rn[t] = lnz;
  __syncthreads();
  for (int off = 128; off > 0; off >>= 1) {
    if (t < off) { rs[t] += rs[t + off]; rn[t] += rn[t + off]; }
    __syncthreads();
  }
  if (t == 0) {
    int bid = blockIdx.y * gridDim.x + blockIdx.x;
    psum[bid] = rs[0];
    pnnz[bid] = rn[0];
  }
}

__global__ __launch_bounds__(256) void k_final(const float* __restrict__ psum,
                                               const uint32_t* __restrict__ pnnz,
                                               float* __restrict__ out) {
  __shared__ float rs[256];
  __shared__ uint32_t rn[256];
  int t = threadIdx.x;
  float s = 0.f; uint32_t nz = 0;
  for (int j = t; j < 1024; j += 256) { s += psum[j]; nz += pnnz[j]; }
  rs[t] = s; rn[t] = nz;
  __syncthreads();
  for (int off = 128; off > 0; off >>= 1) {
    if (t < off) { rs[t] += rs[t + off]; rn[t] += rn[t + off]; }
    __syncthreads();
  }
  if (t == 0) out[0] = rs[0] / (float)rn[0];
}

extern "C" void kernel_launch(void* const* d_in, const int* in_sizes, int n_in,
                              void* d_out, int out_size, void* d_ws, size_t ws_size,
                              hipStream_t stream) {
  (void)in_sizes; (void)n_in; (void)out_size; (void)ws_size;
  const float* d1    = (const float*)d_in[0];
  const float* pfegc = (const float*)d_in[1];
  const float* ppre  = (const float*)d_in[2];
  const float* gt    = (const float*)d_in[3];
  const float* W     = (const float*)d_in[4];
  const float* bfc   = (const float*)d_in[5];
  float* out = (float*)d_out;

  uint8_t* base = (uint8_t*)d_ws;
  uint32_t* aWord   = (uint32_t*)(base + OFF_AWORD);
  uint32_t* blkhist = (uint32_t*)(base + OFF_BLKHIST);
  uint32_t* ghist   = (uint32_t*)(base + OFF_GHIST);
  uint32_t* blkbase = (uint32_t*)(base + OFF_BLKBASE);
  uint32_t* ctrl    = (uint32_t*)(base + OFF_CTRL);
  uint64_t* cand    = (uint64_t*)(base + OFF_CAND);
  float*    va      = (float*)(base + OFF_VA);
  float*    wa      = (float*)(base + OFF_WA);
  float*    psum    = (float*)(base + OFF_PSUM);
  uint32_t* pnnz    = (uint32_t*)(base + OFF_PNNZ);

  // jax.random.key(42), partitionable split: kp = tf(0,42,{0,0}), kn = tf(0,42,{0,1})
  uint32_t kp0 = 0u, kp1 = 0u; threefry2x32_(0u, 42u, kp0, kp1);
  uint32_t kn0 = 0u, kn1 = 1u; threefry2x32_(0u, 42u, kn0, kn1);

  k_maskhist<<<NB0, 256, 0, stream>>>(pfegc, ppre, gt, kp0, kp1, kn0, kn1,
                                      aWord, blkhist);
  k_reduce<<<128, 256, 0, stream>>>(blkhist, ghist);
  k_scan0<<<1, 256, 0, stream>>>(ghist, blkhist, blkbase, ctrl);
  k_compact<<<NB0, 256, 0, stream>>>(aWord, ctrl, blkbase, cand);
  k_selproj<<<2, 256, 0, stream>>>(cand, ctrl, W, bfc, d1, va, wa);
  k_pair<<<dim3(32, 32), 256, 0, stream>>>(va, wa, psum, pnnz);
  k_final<<<1, 256, 0, stream>>>(psum, pnnz, out);
}

// Round 4
// 138.503 us; speedup vs baseline: 11.5722x; 1.0022x over previous
//
#include <hip/hip_runtime.h>
#include <stdint.h>

#define HW       262144u     // 512*512
#define NPIX     1048576u    // 4*HW (pixel index fits in 20 bits)
#define NSEL     2048u       // POS_NUM*B = NEG_NUM*B
#define NSEG     1024u       // one segment per front-block per list
#define SEGCAP   32u         // slots per segment (mean occupancy ~5.3, Poisson tail ~1e-15)
#define DENSECAP 6144u       // LDS gather capacity (mean ~5430, +10 sigma)

// workspace byte offsets (~700 KB total)
#define OFF_SEG     0u        // u64[2][NSEG][SEGCAP] = 512 KB
#define OFF_SEGCNT  524288u   // u32[2][NSEG]         = 8 KB
#define OFF_VA      532480u   // f32[4096*5]          = 80 KB
#define OFF_WA      614400u   // f32[4096*5]          = 80 KB
#define OFF_PSUM    696320u   // f32[1024]
#define OFF_PNNZ    700416u   // u32[1024]

// ---------------- Threefry-2x32-20 (JAX partitionable PRNG) ----------------
#define TF_ROUND(r) { x0 += x1; x1 = (x1 << (r)) | (x1 >> (32 - (r))); x1 ^= x0; }
__host__ __device__ inline void threefry2x32_(uint32_t k0, uint32_t k1,
                                              uint32_t& x0, uint32_t& x1) {
  uint32_t k2 = k0 ^ k1 ^ 0x1BD11BDAu;
  x0 += k0; x1 += k1;
  TF_ROUND(13) TF_ROUND(15) TF_ROUND(26) TF_ROUND(6)
  x0 += k1; x1 += k2 + 1u;
  TF_ROUND(17) TF_ROUND(29) TF_ROUND(16) TF_ROUND(24)
  x0 += k2; x1 += k0 + 2u;
  TF_ROUND(13) TF_ROUND(15) TF_ROUND(26) TF_ROUND(6)
  x0 += k0; x1 += k1 + 3u;
  TF_ROUND(17) TF_ROUND(29) TF_ROUND(16) TF_ROUND(24)
  x0 += k1; x1 += k2 + 4u;
  TF_ROUND(13) TF_ROUND(15) TF_ROUND(26) TF_ROUND(6)
  x0 += k2; x1 += k0 + 5u;
}

// ---------------- front: mask + PRNG + fixed-threshold compaction ----------------
// keep iff top-4 bits of the 23-bit random == 0xF (keep-prob 1/16). The keep-set
// is upward-closed in key order, so as long as >=2048 survive per list (certain,
// E~5430, 48-sigma margin) the exact top-2048 is a subset of the survivors.
__global__ __launch_bounds__(256) void k_front(
    const float* __restrict__ pfegc, const float* __restrict__ ppre,
    const float* __restrict__ gt,
    uint32_t kp0, uint32_t kp1, uint32_t kn0, uint32_t kn1,
    uint64_t* __restrict__ seg, uint32_t* __restrict__ segcnt) {
  __shared__ uint32_t cnt2[2];
  int t = threadIdx.x;
  if (t < 2) cnt2[t] = 0;
  __syncthreads();
  uint32_t b = blockIdx.x;
  uint32_t base = b * 1024u + (uint32_t)t * 4u;
  float4 pf = *(const float4*)(pfegc + base);
  float pfa[4] = { pf.x, pf.y, pf.z, pf.w };
  bool any = (pf.x >= 0.5f) || (pf.y >= 0.5f) || (pf.z >= 0.5f) || (pf.w >= 0.5f);
  if (any) {
    uint32_t hw = base & (HW - 1u);
    uint32_t bb = base >> 18;                 // base..base+3 share the image
    const float* pp = ppre + (size_t)bb * 3u * HW + hw;
    float4 p0 = *(const float4*)pp;
    float4 p1 = *(const float4*)(pp + HW);
    float4 p2 = *(const float4*)(pp + 2u * HW);
    float4 g4 = *(const float4*)(gt + base);
    float p0a[4] = { p0.x, p0.y, p0.z, p0.w };
    float p1a[4] = { p1.x, p1.y, p1.z, p1.w };
    float p2a[4] = { p2.x, p2.y, p2.z, p2.w };
    float ga[4]  = { g4.x, g4.y, g4.z, g4.w };
    #pragma unroll
    for (int j = 0; j < 4; ++j) {
      if (pfa[j] >= 0.5f && p0a[j] >= p1a[j] && p0a[j] >= p2a[j]) {
        uint32_t i = base + (uint32_t)j;
        bool gfg = ga[j] > 0.5f;
        uint32_t x0 = 0u, x1 = i;
        threefry2x32_(gfg ? kp0 : kn0, gfg ? kp1 : kn1, x0, x1);
        uint32_t r23 = (x0 ^ x1) >> 9;
        if ((r23 >> 19) == 0xFu) {            // fixed prefilter, keep-prob 1/16
          uint32_t list = gfg ? 0u : 1u;
          uint32_t r = atomicAdd(&cnt2[list], 1u);     // u32 LDS atomic
          if (r < SEGCAP)
            seg[((size_t)list * NSEG + b) * SEGCAP + r] =
                (1ull << 43) | ((uint64_t)r23 << 20) | (uint64_t)(0xFFFFFu ^ i);
        }
      }
    }
  }
  __syncthreads();
  if (t < 2) {
    uint32_t c = cnt2[t];
    segcnt[(uint32_t)t * NSEG + b] = c < SEGCAP ? c : SEGCAP;
  }
}

// ---------------- select exact top-2048 + project (fused; 1 block/list) ----------------
__global__ __launch_bounds__(256) void k_selproj(
    const uint64_t* __restrict__ seg, const uint32_t* __restrict__ segcnt,
    const float* __restrict__ Wm, const float* __restrict__ bfc,
    const float* __restrict__ d1,
    float* __restrict__ va, float* __restrict__ wa) {
  __shared__ uint64_t dense[DENSECAP];   // 48 KB
  __shared__ uint32_t hist[2048];        // 8 KB
  __shared__ uint32_t part[256];
  __shared__ int gsel;
  __shared__ uint64_t spref;
  __shared__ uint32_t skk;
  __shared__ uint32_t rank;
  __shared__ uint32_t ntot;
  __shared__ float sG[25];
  __shared__ float sGw[4][25];
  int t = threadIdx.x;
  int list = blockIdx.x;
  // ---- G = [W|b]^T [W|b] via shuffle reduction (no atomics) ----
  {
    float4 wr = *(const float4*)(Wm + t * 4);
    float av[5] = { wr.x, wr.y, wr.z, wr.w, bfc[t] };
    int lane = t & 63, wvi = t >> 6;
    #pragma unroll
    for (int p = 0; p < 5; ++p)
      #pragma unroll
      for (int q = p; q < 5; ++q) {
        float g = av[p] * av[q];
        #pragma unroll
        for (int off = 32; off > 0; off >>= 1)
          g += __shfl_xor(g, off, 64);
        if (lane == 0) sGw[wvi][p * 5 + q] = g;
      }
  }
  if (t == 0) { spref = 0ull; skk = NSEL; rank = 0; }
  __syncthreads();
  if (t < 25) {
    int p = t / 5, q = t % 5;
    int pp = p < q ? p : q, qq = p < q ? q : p;
    sG[t] = sGw[0][pp * 5 + qq] + sGw[1][pp * 5 + qq]
          + sGw[2][pp * 5 + qq] + sGw[3][pp * 5 + qq];
  }
  // ---- segment counts -> per-thread bases (order-free; loss is permutation-invariant) ----
  uint32_t c[4]; uint32_t s = 0;
  #pragma unroll
  for (int u = 0; u < 4; ++u) {
    c[u] = segcnt[(uint32_t)list * NSEG + (uint32_t)u * 256u + (uint32_t)t];
    s += c[u];
  }
  part[t] = s;
  __syncthreads();
  for (int off = 1; off < 256; off <<= 1) {
    uint32_t x = part[t];
    uint32_t add = (t >= off) ? part[t - off] : 0u;
    __syncthreads();
    part[t] = x + add;
    __syncthreads();
  }
  uint32_t off0 = part[t] - s;
  if (t == 255) ntot = part[255];
  // ---- gather survivors into LDS ----
  #pragma unroll
  for (int u = 0; u < 4; ++u) {
    const uint64_t* sp = seg +
        ((size_t)list * NSEG + (uint32_t)u * 256u + (uint32_t)t) * SEGCAP;
    for (uint32_t j = 0; j < c[u]; ++j) {
      if (off0 < DENSECAP) dense[off0++] = sp[j];
    }
  }
  __syncthreads();
  uint32_t n = ntot; if (n > DENSECAP) n = DENSECAP;
  // ---- 4-round 11-bit radix select of the exact 2048th-largest key ----
  for (int r = 0; r < 4; ++r) {
    #pragma unroll
    for (int e = 0; e < 8; ++e) hist[t * 8 + e] = 0;
    __syncthreads();
    int csp = 44 - 11 * r;
    int cs = csp - 11;
    uint64_t pref = spref;
    for (uint32_t j = t; j < n; j += 256) {
      uint64_t key = dense[j];
      if ((key >> csp) == pref)
        atomicAdd(&hist[(uint32_t)(key >> cs) & 0x7FFu], 1u);
    }
    __syncthreads();
    uint32_t ss = 0;
    #pragma unroll
    for (int e = 0; e < 8; ++e) ss += hist[t * 8 + e];
    part[t] = ss;
    __syncthreads();
    for (int off = 1; off < 256; off <<= 1) {
      uint32_t x = part[t];
      uint32_t y = (t + off < 256) ? part[t + off] : 0u;
      __syncthreads();
      part[t] = x + y;
      __syncthreads();
    }
    uint32_t k = skk;
    if (part[t] >= k && (t == 255 || part[t + 1] < k)) gsel = t;
    __syncthreads();
    if (t == 0) {
      int g = gsel;
      uint32_t cum = (g < 255) ? part[g + 1] : 0u;
      int d = g * 8;
      for (int e = g * 8 + 7; e >= g * 8; --e) {
        uint32_t he = hist[e];
        if (cum + he >= k) { d = e; break; }
        cum += he;
      }
      skk = k - cum;
      spref = (pref << 11) | (uint64_t)(uint32_t)d;
    }
    __syncthreads();
  }
  // ---- collect survivors and project: v = y/|proj|, w = G v ----
  uint64_t thr = spref;
  for (uint32_t j = t; j < n; j += 256) {
    uint64_t key = dense[j];
    if (key >= thr) {
      uint32_t rr = atomicAdd(&rank, 1u);                // u32 LDS atomic
      if (rr < NSEL) {
        uint32_t idx = 0xFFFFFu ^ (uint32_t)(key & 0xFFFFFu);
        uint32_t hw = idx & (HW - 1u);
        uint32_t bb = idx >> 18;
        const float* f = d1 + ((size_t)bb << 20) + hw;
        float y[5] = { f[0], f[HW], f[2u * HW], f[3u * HW], 1.0f };
        float z[5]; float n2 = 0.f;
        #pragma unroll
        for (int p = 0; p < 5; ++p) {
          float acc = 0.f;
          #pragma unroll
          for (int q = 0; q < 5; ++q) acc += sG[p * 5 + q] * y[q];
          z[p] = acc; n2 += acc * y[p];                  // = |proj|^2
        }
        n2 = fmaxf(n2, 0.f);
        float inv = 1.0f / fmaxf(sqrtf(n2), 1e-8f);
        uint32_t s5 = ((uint32_t)list * NSEL + rr) * 5u;
        #pragma unroll
        for (int p = 0; p < 5; ++p) {
          va[s5 + p] = y[p] * inv;
          wa[s5 + p] = z[p] * inv;
        }
      }
    }
  }
}

// ---------------- pairwise loss: per-block partials, no global atomics ----------------
__global__ __launch_bounds__(256) void k_pair(
    const float* __restrict__ va, const float* __restrict__ wa,
    float* __restrict__ psum, uint32_t* __restrict__ pnnz) {
  __shared__ float sv[128 * 5], sw[128 * 5];
  int i0 = blockIdx.x * 128, j0 = blockIdx.y * 128;
  int t = threadIdx.x;
  for (int u = t; u < 640; u += 256) { sv[u] = va[i0 * 5 + u]; sw[u] = wa[j0 * 5 + u]; }
  __syncthreads();
  int ty = t >> 4, tx = t & 15;
  float rv[8][5], rw[8][5];
  #pragma unroll
  for (int a = 0; a < 8; ++a)
    #pragma unroll
    for (int p = 0; p < 5; ++p) {
      rv[a][p] = sv[(ty * 8 + a) * 5 + p];
      rw[a][p] = sw[(tx * 8 + a) * 5 + p];
    }
  float lsum = 0.f; uint32_t lnz = 0;
  #pragma unroll
  for (int a = 0; a < 8; ++a) {
    int gi = i0 + ty * 8 + a;
    #pragma unroll
    for (int q = 0; q < 8; ++q) {
      int gj = j0 + tx * 8 + q;
      float c = rv[a][0]*rw[q][0] + rv[a][1]*rw[q][1] + rv[a][2]*rw[q][2]
              + rv[a][3]*rw[q][3] + rv[a][4]*rw[q][4];
      float s = c * 10.0f;                     // / TAU
      if (gi != gj) {
        if (((gi ^ gj) & 2048) == 0) {         // same block (pos-pos / neg-neg)
          float m = fmaxf(0.5f - s, 0.f);
          lsum += m * m;
          lnz += (m > 0.f) ? 1u : 0u;
        } else {                               // cross block
          lsum += s * s;
          lnz += (s != 0.f) ? 1u : 0u;
        }
      }
    }
  }
  __shared__ float rs[256];
  __shared__ uint32_t rn[256];
  rs[t] = lsum; rn[t] = lnz;
  __syncthreads();
  for (int off = 128; off > 0; off >>= 1) {
    if (t < off) { rs[t] += rs[t + off]; rn[t] += rn[t + off]; }
    __syncthreads();
  }
  if (t == 0) {
    int bid = blockIdx.y * gridDim.x + blockIdx.x;
    psum[bid] = rs[0];
    pnnz[bid] = rn[0];
  }
}

__global__ __launch_bounds__(256) void k_final(const float* __restrict__ psum,
                                               const uint32_t* __restrict__ pnnz,
                                               float* __restrict__ out) {
  __shared__ float rs[256];
  __shared__ uint32_t rn[256];
  int t = threadIdx.x;
  float s = 0.f; uint32_t nz = 0;
  for (int j = t; j < 1024; j += 256) { s += psum[j]; nz += pnnz[j]; }
  rs[t] = s; rn[t] = nz;
  __syncthreads();
  for (int off = 128; off > 0; off >>= 1) {
    if (t < off) { rs[t] += rs[t + off]; rn[t] += rn[t + off]; }
    __syncthreads();
  }
  if (t == 0) out[0] = rs[0] / (float)rn[0];
}

extern "C" void kernel_launch(void* const* d_in, const int* in_sizes, int n_in,
                              void* d_out, int out_size, void* d_ws, size_t ws_size,
                              hipStream_t stream) {
  (void)in_sizes; (void)n_in; (void)out_size; (void)ws_size;
  const float* d1    = (const float*)d_in[0];
  const float* pfegc = (const float*)d_in[1];
  const float* ppre  = (const float*)d_in[2];
  const float* gt    = (const float*)d_in[3];
  const float* W     = (const float*)d_in[4];
  const float* bfc   = (const float*)d_in[5];
  float* out = (float*)d_out;

  uint8_t* base = (uint8_t*)d_ws;
  uint64_t* seg    = (uint64_t*)(base + OFF_SEG);
  uint32_t* segcnt = (uint32_t*)(base + OFF_SEGCNT);
  float*    va     = (float*)(base + OFF_VA);
  float*    wa     = (float*)(base + OFF_WA);
  float*    psum   = (float*)(base + OFF_PSUM);
  uint32_t* pnnz   = (uint32_t*)(base + OFF_PNNZ);

  // jax.random.key(42), partitionable split: kp = tf(0,42,{0,0}), kn = tf(0,42,{0,1})
  uint32_t kp0 = 0u, kp1 = 0u; threefry2x32_(0u, 42u, kp0, kp1);
  uint32_t kn0 = 0u, kn1 = 1u; threefry2x32_(0u, 42u, kn0, kn1);

  k_front<<<NSEG, 256, 0, stream>>>(pfegc, ppre, gt, kp0, kp1, kn0, kn1, seg, segcnt);
  k_selproj<<<2, 256, 0, stream>>>(seg, segcnt, W, bfc, d1, va, wa);
  k_pair<<<dim3(32, 32), 256, 0, stream>>>(va, wa, psum, pnnz);
  k_final<<<1, 256, 0, stream>>>(psum, pnnz, out);
}

// Round 5
// 130.734 us; speedup vs baseline: 12.2599x; 1.0594x over previous
//
#include <hip/hip_runtime.h>
#include <stdint.h>

#define HW       262144u     // 512*512
#define NPIX     1048576u    // 4*HW (pixel index fits in 20 bits)
#define NSEL     2048u       // POS_NUM*B = NEG_NUM*B
#define NSEG     1024u       // one segment per front-block per list
#define SEGCAP   16u         // slots/segment (keep-prob 1/32 -> mean ~2.6; P(overflow)~3e-5, harmless)
#define DENSECAP 3584u       // LDS gather capacity (mean ~2715, +16 sigma)

// workspace byte offsets (~450 KB total)
#define OFF_SEG     0u        // u64[2][NSEG][SEGCAP] = 256 KB (zero-filled unused slots)
#define OFF_IDX     262144u   // u32[4096] pos then neg
#define OFF_VA      278528u   // f32[4096*5]
#define OFF_WA      360448u   // f32[4096*5]
#define OFF_PSUM    442368u   // f32[1024]
#define OFF_PNNZ    446464u   // u32[1024]

// ---------------- Threefry-2x32-20 (JAX partitionable PRNG) ----------------
#define TF_ROUND(r) { x0 += x1; x1 = (x1 << (r)) | (x1 >> (32 - (r))); x1 ^= x0; }
__host__ __device__ inline void threefry2x32_(uint32_t k0, uint32_t k1,
                                              uint32_t& x0, uint32_t& x1) {
  uint32_t k2 = k0 ^ k1 ^ 0x1BD11BDAu;
  x0 += k0; x1 += k1;
  TF_ROUND(13) TF_ROUND(15) TF_ROUND(26) TF_ROUND(6)
  x0 += k1; x1 += k2 + 1u;
  TF_ROUND(17) TF_ROUND(29) TF_ROUND(16) TF_ROUND(24)
  x0 += k2; x1 += k0 + 2u;
  TF_ROUND(13) TF_ROUND(15) TF_ROUND(26) TF_ROUND(6)
  x0 += k0; x1 += k1 + 3u;
  TF_ROUND(17) TF_ROUND(29) TF_ROUND(16) TF_ROUND(24)
  x0 += k1; x1 += k2 + 4u;
  TF_ROUND(13) TF_ROUND(15) TF_ROUND(26) TF_ROUND(6)
  x0 += k2; x1 += k0 + 5u;
}

// ---------------- front: mask + PRNG + fixed-threshold compaction ----------------
// keep iff top-5 bits of the 23-bit random == 0x1F (keep-prob 1/32). Keep-set is
// upward-closed in key order; E[survivors] ~2700 >= 2048 at ~10 sigma, so the
// exact top-2048 is a subset of the survivors. Unused slots are zeroed (bit43
// marker distinguishes real keys), so the back-end can sweep the array blindly.
__global__ __launch_bounds__(256) void k_front(
    const float* __restrict__ pfegc, const float* __restrict__ ppre,
    const float* __restrict__ gt,
    uint32_t kp0, uint32_t kp1, uint32_t kn0, uint32_t kn1,
    uint64_t* __restrict__ seg) {
  __shared__ uint32_t cnt2[2];
  int t = threadIdx.x;
  uint32_t b = blockIdx.x;
  if (t < 2) cnt2[t] = 0;
  if (t < 2 * (int)SEGCAP) {           // zero-fill this block's two segments
    uint32_t list = (uint32_t)t / SEGCAP, slot = (uint32_t)t % SEGCAP;
    seg[((size_t)list * NSEG + b) * SEGCAP + slot] = 0ull;
  }
  __syncthreads();
  uint32_t base = b * 1024u + (uint32_t)t * 4u;
  float4 pf = *(const float4*)(pfegc + base);
  float pfa[4] = { pf.x, pf.y, pf.z, pf.w };
  bool any = (pf.x >= 0.5f) || (pf.y >= 0.5f) || (pf.z >= 0.5f) || (pf.w >= 0.5f);
  if (any) {
    uint32_t hw = base & (HW - 1u);
    uint32_t bb = base >> 18;                 // base..base+3 share the image
    const float* pp = ppre + (size_t)bb * 3u * HW + hw;
    float4 p0 = *(const float4*)pp;
    float4 p1 = *(const float4*)(pp + HW);
    float4 p2 = *(const float4*)(pp + 2u * HW);
    float4 g4 = *(const float4*)(gt + base);
    float p0a[4] = { p0.x, p0.y, p0.z, p0.w };
    float p1a[4] = { p1.x, p1.y, p1.z, p1.w };
    float p2a[4] = { p2.x, p2.y, p2.z, p2.w };
    float ga[4]  = { g4.x, g4.y, g4.z, g4.w };
    #pragma unroll
    for (int j = 0; j < 4; ++j) {
      if (pfa[j] >= 0.5f && p0a[j] >= p1a[j] && p0a[j] >= p2a[j]) {
        uint32_t i = base + (uint32_t)j;
        bool gfg = ga[j] > 0.5f;
        uint32_t x0 = 0u, x1 = i;
        threefry2x32_(gfg ? kp0 : kn0, gfg ? kp1 : kn1, x0, x1);
        uint32_t r23 = (x0 ^ x1) >> 9;
        if ((r23 >> 18) == 0x1Fu) {           // fixed prefilter, keep-prob 1/32
          uint32_t list = gfg ? 0u : 1u;
          uint32_t r = atomicAdd(&cnt2[list], 1u);     // u32 LDS atomic, rare
          if (r < SEGCAP)
            seg[((size_t)list * NSEG + b) * SEGCAP + r] =
                (1ull << 43) | ((uint64_t)r23 << 20) | (uint64_t)(0xFFFFFu ^ i);
        }
      }
    }
  }
}

// ---------------- select exact top-2048 (1 block/list) ----------------
// Coalesced sweep of the 128 KB segment half; ballot-aggregated LDS push
// (1 atomic per wave); 4-round 11-bit radix select; ballot-aggregated collect.
__global__ __launch_bounds__(256) void k_sel(
    const uint64_t* __restrict__ seg, uint32_t* __restrict__ idxbuf) {
  __shared__ uint64_t dense[DENSECAP];   // 28 KB
  __shared__ uint32_t hist[2048];        // 8 KB
  __shared__ uint32_t part[256];
  __shared__ uint32_t cnt, rank, skk;
  __shared__ int gsel;
  __shared__ uint64_t spref;
  int t = threadIdx.x;
  int list = blockIdx.x;
  uint32_t lane = (uint32_t)t & 63u;
  if (t == 0) { cnt = 0; rank = 0; spref = 0ull; skk = NSEL; }
  __syncthreads();
  const uint64_t* sp = seg + (size_t)list * NSEG * SEGCAP;
  // ---- coalesced sweep: 16384 u64 in 32 iterations of u64x2 per thread ----
  for (int it = 0; it < 32; ++it) {
    uint32_t g = (uint32_t)it * 512u + (uint32_t)t * 2u;
    uint64_t k0 = sp[g];
    uint64_t k1 = sp[g + 1u];
    #pragma unroll
    for (int h = 0; h < 2; ++h) {
      uint64_t key = h ? k1 : k0;
      bool v = (key >> 43) != 0ull;
      unsigned long long m = __ballot(v);
      uint32_t bs = 0;
      if (lane == 0) bs = atomicAdd(&cnt, (uint32_t)__popcll(m));
      bs = (uint32_t)__shfl((int)bs, 0, 64);
      if (v) {
        uint32_t s = bs + (uint32_t)__popcll(m & ((1ull << lane) - 1ull));
        if (s < DENSECAP) dense[s] = key;
      }
    }
  }
  __syncthreads();
  uint32_t n = cnt; if (n > DENSECAP) n = DENSECAP;
  // ---- 4-round 11-bit radix select of the exact 2048th-largest key ----
  for (int r = 0; r < 4; ++r) {
    #pragma unroll
    for (int e = 0; e < 8; ++e) hist[t * 8 + e] = 0;
    __syncthreads();
    int csp = 44 - 11 * r;
    int cs = csp - 11;
    uint64_t pref = spref;
    for (uint32_t j = t; j < n; j += 256) {
      uint64_t key = dense[j];
      if ((key >> csp) == pref)
        atomicAdd(&hist[(uint32_t)(key >> cs) & 0x7FFu], 1u);
    }
    __syncthreads();
    uint32_t ss = 0;
    #pragma unroll
    for (int e = 0; e < 8; ++e) ss += hist[t * 8 + e];
    part[t] = ss;
    __syncthreads();
    for (int off = 1; off < 256; off <<= 1) {
      uint32_t x = part[t];
      uint32_t y = (t + off < 256) ? part[t + off] : 0u;
      __syncthreads();
      part[t] = x + y;
      __syncthreads();
    }
    uint32_t k = skk;
    if (part[t] >= k && (t == 255 || part[t + 1] < k)) gsel = t;
    __syncthreads();
    if (t == 0) {
      int g = gsel;
      uint32_t cum = (g < 255) ? part[g + 1] : 0u;
      int d = g * 8;
      for (int e = g * 8 + 7; e >= g * 8; --e) {
        uint32_t he = hist[e];
        if (cum + he >= k) { d = e; break; }
        cum += he;
      }
      skk = k - cum;
      spref = (pref << 11) | (uint64_t)(uint32_t)d;
    }
    __syncthreads();
  }
  // ---- collect survivor indices (ballot-aggregated ranks) ----
  uint64_t thr = spref;
  uint32_t niter = (n + 255u) >> 8;
  for (uint32_t it2 = 0; it2 < niter; ++it2) {
    uint32_t j = it2 * 256u + (uint32_t)t;
    uint64_t key = 0ull;
    bool v = false;
    if (j < n) { key = dense[j]; v = key >= thr; }
    unsigned long long m = __ballot(v);
    uint32_t bs = 0;
    if (lane == 0) bs = atomicAdd(&rank, (uint32_t)__popcll(m));
    bs = (uint32_t)__shfl((int)bs, 0, 64);
    if (v) {
      uint32_t s = bs + (uint32_t)__popcll(m & ((1ull << lane) - 1ull));
      if (s < NSEL)
        idxbuf[(uint32_t)list * NSEL + s] = 0xFFFFFu ^ (uint32_t)(key & 0xFFFFFu);
    }
  }
}

// ---------------- project: v = y/|proj|, w = G v (1 point/thread) ----------------
__global__ __launch_bounds__(256) void k_proj(
    const uint32_t* __restrict__ idxbuf, const float* __restrict__ Wm,
    const float* __restrict__ bfc, const float* __restrict__ d1,
    float* __restrict__ va, float* __restrict__ wa) {
  __shared__ float sG[25];
  __shared__ float sGw[4][25];
  int t = threadIdx.x;
  // ---- G = [W|b]^T [W|b] via shuffle reduction (no atomics) ----
  {
    float4 wr = *(const float4*)(Wm + t * 4);
    float av[5] = { wr.x, wr.y, wr.z, wr.w, bfc[t] };
    int lane = t & 63, wvi = t >> 6;
    #pragma unroll
    for (int p = 0; p < 5; ++p)
      #pragma unroll
      for (int q = p; q < 5; ++q) {
        float g = av[p] * av[q];
        #pragma unroll
        for (int off = 32; off > 0; off >>= 1)
          g += __shfl_xor(g, off, 64);
        if (lane == 0) sGw[wvi][p * 5 + q] = g;
      }
  }
  __syncthreads();
  if (t < 25) {
    int p = t / 5, q = t % 5;
    int pp = p < q ? p : q, qq = p < q ? q : p;
    sG[t] = sGw[0][pp * 5 + qq] + sGw[1][pp * 5 + qq]
          + sGw[2][pp * 5 + qq] + sGw[3][pp * 5 + qq];
  }
  __syncthreads();
  uint32_t tg = blockIdx.x * 256u + (uint32_t)t;      // 0..4095
  uint32_t idx = idxbuf[tg] & (NPIX - 1u);
  uint32_t hw = idx & (HW - 1u);
  uint32_t bb = idx >> 18;
  const float* f = d1 + ((size_t)bb << 20) + hw;
  float y[5] = { f[0], f[HW], f[2u * HW], f[3u * HW], 1.0f };
  float z[5]; float n2 = 0.f;
  #pragma unroll
  for (int p = 0; p < 5; ++p) {
    float acc = 0.f;
    #pragma unroll
    for (int q = 0; q < 5; ++q) acc += sG[p * 5 + q] * y[q];
    z[p] = acc; n2 += acc * y[p];                     // = |proj|^2
  }
  n2 = fmaxf(n2, 0.f);
  float inv = 1.0f / fmaxf(sqrtf(n2), 1e-8f);
  uint32_t s5 = tg * 5u;
  #pragma unroll
  for (int p = 0; p < 5; ++p) {
    va[s5 + p] = y[p] * inv;
    wa[s5 + p] = z[p] * inv;
  }
}

// ---------------- pairwise loss: per-block partials, no global atomics ----------------
__global__ __launch_bounds__(256) void k_pair(
    const float* __restrict__ va, const float* __restrict__ wa,
    float* __restrict__ psum, uint32_t* __restrict__ pnnz) {
  __shared__ float sv[128 * 5], sw[128 * 5];
  int i0 = blockIdx.x * 128, j0 = blockIdx.y * 128;
  int t = threadIdx.x;
  for (int u = t; u < 640; u += 256) { sv[u] = va[i0 * 5 + u]; sw[u] = wa[j0 * 5 + u]; }
  __syncthreads();
  int ty = t >> 4, tx = t & 15;
  float rv[8][5], rw[8][5];
  #pragma unroll
  for (int a = 0; a < 8; ++a)
    #pragma unroll
    for (int p = 0; p < 5; ++p) {
      rv[a][p] = sv[(ty * 8 + a) * 5 + p];
      rw[a][p] = sw[(tx * 8 + a) * 5 + p];
    }
  float lsum = 0.f; uint32_t lnz = 0;
  #pragma unroll
  for (int a = 0; a < 8; ++a) {
    int gi = i0 + ty * 8 + a;
    #pragma unroll
    for (int q = 0; q < 8; ++q) {
      int gj = j0 + tx * 8 + q;
      float c = rv[a][0]*rw[q][0] + rv[a][1]*rw[q][1] + rv[a][2]*rw[q][2]
              + rv[a][3]*rw[q][3] + rv[a][4]*rw[q][4];
      float s = c * 10.0f;                     // / TAU
      if (gi != gj) {
        if (((gi ^ gj) & 2048) == 0) {         // same block (pos-pos / neg-neg)
          float m = fmaxf(0.5f - s, 0.f);
          lsum += m * m;
          lnz += (m > 0.f) ? 1u : 0u;
        } else {                               // cross block
          lsum += s * s;
          lnz += (s != 0.f) ? 1u : 0u;
        }
      }
    }
  }
  __shared__ float rs[256];
  __shared__ uint32_t rn[256];
  rs[t] = lsum; rn[t] = lnz;
  __syncthreads();
  for (int off = 128; off > 0; off >>= 1) {
    if (t < off) { rs[t] += rs[t + off]; rn[t] += rn[t + off]; }
    __syncthreads();
  }
  if (t == 0) {
    int bid = blockIdx.y * gridDim.x + blockIdx.x;
    psum[bid] = rs[0];
    pnnz[bid] = rn[0];
  }
}

__global__ __launch_bounds__(256) void k_final(const float* __restrict__ psum,
                                               const uint32_t* __restrict__ pnnz,
                                               float* __restrict__ out) {
  __shared__ float rs[256];
  __shared__ uint32_t rn[256];
  int t = threadIdx.x;
  float s = 0.f; uint32_t nz = 0;
  for (int j = t; j < 1024; j += 256) { s += psum[j]; nz += pnnz[j]; }
  rs[t] = s; rn[t] = nz;
  __syncthreads();
  for (int off = 128; off > 0; off >>= 1) {
    if (t < off) { rs[t] += rs[t + off]; rn[t] += rn[t + off]; }
    __syncthreads();
  }
  if (t == 0) out[0] = rs[0] / (float)rn[0];
}

extern "C" void kernel_launch(void* const* d_in, const int* in_sizes, int n_in,
                              void* d_out, int out_size, void* d_ws, size_t ws_size,
                              hipStream_t stream) {
  (void)in_sizes; (void)n_in; (void)out_size; (void)ws_size;
  const float* d1    = (const float*)d_in[0];
  const float* pfegc = (const float*)d_in[1];
  const float* ppre  = (const float*)d_in[2];
  const float* gt    = (const float*)d_in[3];
  const float* W     = (const float*)d_in[4];
  const float* bfc   = (const float*)d_in[5];
  float* out = (float*)d_out;

  uint8_t* base = (uint8_t*)d_ws;
  uint64_t* seg    = (uint64_t*)(base + OFF_SEG);
  uint32_t* idxbuf = (uint32_t*)(base + OFF_IDX);
  float*    va     = (float*)(base + OFF_VA);
  float*    wa     = (float*)(base + OFF_WA);
  float*    psum   = (float*)(base + OFF_PSUM);
  uint32_t* pnnz   = (uint32_t*)(base + OFF_PNNZ);

  // jax.random.key(42), partitionable split: kp = tf(0,42,{0,0}), kn = tf(0,42,{0,1})
  uint32_t kp0 = 0u, kp1 = 0u; threefry2x32_(0u, 42u, kp0, kp1);
  uint32_t kn0 = 0u, kn1 = 1u; threefry2x32_(0u, 42u, kn0, kn1);

  k_front<<<NSEG, 256, 0, stream>>>(pfegc, ppre, gt, kp0, kp1, kn0, kn1, seg);
  k_sel<<<2, 256, 0, stream>>>(seg, idxbuf);
  k_proj<<<16, 256, 0, stream>>>(idxbuf, W, bfc, d1, va, wa);
  k_pair<<<dim3(32, 32), 256, 0, stream>>>(va, wa, psum, pnnz);
  k_final<<<1, 256, 0, stream>>>(psum, pnnz, out);
}